// Round 1
// baseline (70767.212 us; speedup 1.0000x reference)
//
#include <hip/hip_runtime.h>

// ---------------------------------------------------------------------------
// Teacher_model_7464653160858: embed+BN -> 3x GRU(1024, reset_after) -> dense+softmax
// B=64, T=512, E=256, U=1024, V=512.
// Strategy: persistent cooperative-style kernel, 256 WGs (1/CU), grid barrier
// per timestep (1536 barriers). bf16 MFMA 16x16x32, fp32 accum. Weights packed
// transposed bf16; ~136KB LDS-resident per WG. h carried in fp32 registers.
// ---------------------------------------------------------------------------

typedef short bf16x8 __attribute__((ext_vector_type(8)));
typedef float f32x4 __attribute__((ext_vector_type(4)));
typedef unsigned short ushort_t;

#define MFMA16(a, b, c) __builtin_amdgcn_mfma_f32_16x16x32_bf16((a), (b), (c), 0, 0, 0)

#define BB 64
#define TT 512
#define EE 256
#define UU 1024
#define NSLOT 513          // slot 0 = h0, slot t+1 = output of step t
#define LSTRIDE 1416       // LDS row stride in elems (1408 resident + 8 pad -> bank-friendly)
#define NWG 256

__device__ __forceinline__ float bf2f(ushort_t h) {
    return __uint_as_float(((unsigned)h) << 16);
}
__device__ __forceinline__ ushort_t f2bf(float f) {
    unsigned u = __float_as_uint(f);
    u += 0x7FFFu + ((u >> 16) & 1u);   // round-to-nearest-even
    return (ushort_t)(u >> 16);
}
__device__ __forceinline__ float sigmf(float x) { return 1.f / (1.f + __expf(-x)); }
__device__ __forceinline__ float tanhfast(float x) {
    float e = __expf(2.f * x);
    return 1.f - 2.f / (e + 1.f);      // safe at +-inf
}

// Two-level grid barrier: 16 group counters (128B apart) -> root counter.
// bar[g*32] for g in 0..15, root at bar[512]. All zeroed via hipMemsetAsync.
__device__ __forceinline__ void gridbar(unsigned* bar, unsigned nbar) {
    __threadfence();              // release: drain + wb L2 (agent scope)
    __syncthreads();
    if (threadIdx.x == 0) {
        const unsigned g = blockIdx.x >> 4;
        unsigned old = __hip_atomic_fetch_add(&bar[g * 32], 1u, __ATOMIC_ACQ_REL,
                                              __HIP_MEMORY_SCOPE_AGENT);
        if (old + 1u == nbar * 16u) {   // last of this group's 16 WGs for this barrier
            __hip_atomic_fetch_add(&bar[512], 1u, __ATOMIC_ACQ_REL,
                                   __HIP_MEMORY_SCOPE_AGENT);
        }
        while (__hip_atomic_load(&bar[512], __ATOMIC_RELAXED,
                                 __HIP_MEMORY_SCOPE_AGENT) < nbar * 16u) {
            __builtin_amdgcn_s_sleep(1);
        }
    }
    __syncthreads();
    __threadfence();              // acquire: invalidate stale L1/L2
}

// ---------------------------------------------------------------------------
// K1: pack weights -> WT[c][k] = bf16( k<D ? Wk[k][c] : Wr[k-D][c] ), KT = D+U
// grid (KT/64, 3072/64), block 256. LDS tile transpose, coalesced both sides.
// ---------------------------------------------------------------------------
__global__ __launch_bounds__(256, 1) void pack_weights(
    const float* __restrict__ Wk, const float* __restrict__ Wr,
    ushort_t* __restrict__ WT, int D, int KT)
{
    __shared__ ushort_t tile[64][72];
    const int kt0 = blockIdx.x * 64;
    const int ct0 = blockIdx.y * 64;
    const int tx = threadIdx.x & 63;
    const int ty = threadIdx.x >> 6;
#pragma unroll
    for (int i = 0; i < 16; ++i) {
        int k = kt0 + ty * 16 + i;
        int c = ct0 + tx;
        float v = (k < D) ? Wk[(size_t)k * 3072 + c] : Wr[(size_t)(k - D) * 3072 + c];
        tile[ty * 16 + i][tx] = f2bf(v);
    }
    __syncthreads();
#pragma unroll
    for (int i = 0; i < 16; ++i) {
        int c = ct0 + ty * 16 + i;
        WT[(size_t)c * KT + kt0 + tx] = tile[tx][ty * 16 + i];
    }
}

// ---------------------------------------------------------------------------
// K2: BN-folded embedding table (512x256 bf16) + zero seqA slot 0 (h0 = 0)
// ---------------------------------------------------------------------------
__global__ __launch_bounds__(256, 1) void embed_bn(
    const float* __restrict__ emb,
    const float* __restrict__ gamma, const float* __restrict__ beta,
    const float* __restrict__ mean, const float* __restrict__ var,
    ushort_t* __restrict__ embBN, ushort_t* __restrict__ seqA)
{
    const int idx = blockIdx.x * 256 + threadIdx.x;
    const int total = 512 * 256;
    if (idx < total) {
        const int e = idx & 255;
        const float sc = gamma[e] * rsqrtf(var[e] + 1e-3f);
        const float sh = beta[e] - mean[e] * sc;
        embBN[idx] = f2bf(fmaf(emb[idx], sc, sh));
    } else {
        const int j = idx - total;
        if (j < 64 * 1024) {
            const int b = j >> 10, u = j & 1023;
            seqA[(size_t)b * NSLOT * UU + u] = 0;
        }
    }
}

// ---------------------------------------------------------------------------
// K3: persistent GRU. 256 WGs x 256 thr. group = wg>>6 (16 batch rows),
// ubase = (wg&63)*16. Each WG computes its 16x48 gate tile per step; 4 waves
// split K 4-ways; LDS reduction; wave0 does gating + h store.
// ---------------------------------------------------------------------------
__global__ __launch_bounds__(256, 1) void gru_persistent(
    const int* __restrict__ tokens,
    const ushort_t* __restrict__ embBN,
    ushort_t* __restrict__ seqA, ushort_t* __restrict__ seqB,
    const ushort_t* __restrict__ WT0, const ushort_t* __restrict__ WT1,
    const ushort_t* __restrict__ WT2,
    const float* __restrict__ gb0, const float* __restrict__ gb1,
    const float* __restrict__ gb2,
    float* __restrict__ hfinal, unsigned* __restrict__ bar)
{
    __shared__ ushort_t ldsW[48 * LSTRIDE];   // 135,936 B resident weights
    __shared__ f32x4 ldsRed[16 * 64];         // 16,384 B cross-wave reduction

    const int tid = threadIdx.x;
    const int wg = blockIdx.x;
    const int w = tid >> 6;          // wave 0..3
    const int lane = tid & 63;
    const int n = lane & 15;         // u-col within 16 / A-row m
    const int quad = lane >> 4;      // k sub-offset *8
    const int rowbase = (wg >> 6) * 16;
    const int ubase = (wg & 63) * 16;
    const int u_ = ubase + n;
    unsigned nbar = 0;

    for (int l = 0; l < 3; ++l) {
        const int D = (l == 0) ? EE : UU;
        const int KT = D + UU;
        const ushort_t* WT = (l == 0) ? WT0 : ((l == 1) ? WT1 : WT2);
        const float* gb = (l == 0) ? gb0 : ((l == 1) ? gb1 : gb2);
        ushort_t* hseq = (l == 1) ? seqB : seqA;               // this layer's h slots
        const ushort_t* xseq = (l == 0) ? (const ushort_t*)0
                                        : ((l == 1) ? seqA : seqB); // prev layer seq

        // ---- stage resident weight slice into LDS ----
        // l==0: all 1280 k resident. l>=1: k in [0,384) at kl=k, k in [1024,2048) at kl=k-640.
        const int RES = (l == 0) ? 1280 : 1408;
        const int rv = RES / 8;
        for (int idx = tid; idx < 48 * rv; idx += 256) {
            int row = idx / rv;
            int kk = (idx - row * rv) * 8;
            int g = row >> 4, i = row & 15;
            int c = g * UU + ubase + i;
            int kg = (l == 0) ? kk : (kk < 384 ? kk : kk + 640);
            *(bf16x8*)(ldsW + row * LSTRIDE + kk) =
                *(const bf16x8*)(WT + (size_t)c * KT + kg);
        }
        __syncthreads();

        const ushort_t* lB0 = ldsW + (0 * 16 + n) * LSTRIDE + quad * 8;
        const ushort_t* lB1 = ldsW + (1 * 16 + n) * LSTRIDE + quad * 8;
        const ushort_t* lB2 = ldsW + (2 * 16 + n) * LSTRIDE + quad * 8;
        const ushort_t* gB0 = WT + (size_t)(0 * UU + u_) * KT + quad * 8;
        const ushort_t* gB1 = WT + (size_t)(1 * UU + u_) * KT + quad * 8;
        const ushort_t* gB2 = WT + (size_t)(2 * UU + u_) * KT + quad * 8;

        // biases (Keras reset_after: b[0]=input, b[1]=recurrent)
        const float bzz = gb[u_] + gb[3 * UU + u_];
        const float brr = gb[UU + u_] + gb[3 * UU + UU + u_];
        const float bxh = gb[2 * UU + u_];
        const float brh = gb[3 * UU + 2 * UU + u_];

        const int bm = rowbase + n;   // A-frag batch row for this lane
        const ushort_t* xrowbase = (l == 0) ? (const ushort_t*)0
                                            : (xseq + (size_t)bm * NSLOT * UU);
        const ushort_t* hrowbase = hseq + (size_t)bm * NSLOT * UU;

        // fp32 h carried in registers for wave0's 4 (row,col) slots
        float hcur[4];
        {
            const ushort_t* hb = (l == 0) ? hseq : xseq;
            const size_t s0 = (l == 0) ? 0 : 512;
#pragma unroll
            for (int i = 0; i < 4; ++i)
                hcur[i] = bf2f(hb[((size_t)(rowbase + quad * 4 + i) * NSLOT + s0) * UU + u_]);
        }

        const int CH = KT >> 5;       // k-chunks of 32: 40 or 64
        const int cpw = CH >> 2;      // chunks per wave
        const int c0 = w * cpw, c1 = c0 + cpw;

        for (int t = 0; t < TT; ++t) {
            const ushort_t* xk;
            if (l == 0) {
                const int tok = tokens[(size_t)bm * TT + t];
                xk = embBN + (size_t)tok * EE + quad * 8;
            } else {
                xk = xrowbase + (size_t)(t + 1) * UU + quad * 8;  // prev layer output at t
            }
            const ushort_t* hk = (t == 0)
                ? ((l == 0) ? (hrowbase + quad * 8)                               // slot 0 (zeros)
                            : (xseq + ((size_t)bm * NSLOT + 512) * UU + quad * 8)) // prev layer final
                : (hrowbase + (size_t)t * UU + quad * 8);

            f32x4 accZ = {0.f, 0.f, 0.f, 0.f};
            f32x4 accR = accZ, accXH = accZ, accRH = accZ;

#pragma unroll 8
            for (int kc = c0; kc < c1; ++kc) {
                const int k0 = kc * 32;
                const bool isX = (k0 < D);
                bf16x8 a = isX ? *(const bf16x8*)(xk + k0)
                               : *(const bf16x8*)(hk + (k0 - D));
                bf16x8 b0f, b1f, b2f;
                if (l == 0 || k0 < 384) {
                    b0f = *(const bf16x8*)(lB0 + k0);
                    b1f = *(const bf16x8*)(lB1 + k0);
                    b2f = *(const bf16x8*)(lB2 + k0);
                } else if (k0 < 1024) {   // streamed from L2
                    b0f = *(const bf16x8*)(gB0 + k0);
                    b1f = *(const bf16x8*)(gB1 + k0);
                    b2f = *(const bf16x8*)(gB2 + k0);
                } else {                  // Wr resident at kl = k0-640
                    const int kl = k0 - 640;
                    b0f = *(const bf16x8*)(lB0 + kl);
                    b1f = *(const bf16x8*)(lB1 + kl);
                    b2f = *(const bf16x8*)(lB2 + kl);
                }
                accZ = MFMA16(a, b0f, accZ);
                accR = MFMA16(a, b1f, accR);
                if (isX) accXH = MFMA16(a, b2f, accXH);
                else     accRH = MFMA16(a, b2f, accRH);
            }

            ldsRed[(w * 4 + 0) * 64 + lane] = accZ;
            ldsRed[(w * 4 + 1) * 64 + lane] = accR;
            ldsRed[(w * 4 + 2) * 64 + lane] = accXH;
            ldsRed[(w * 4 + 3) * 64 + lane] = accRH;
            __syncthreads();

            if (w == 0) {
                f32x4 tZ = ldsRed[0 * 64 + lane] + ldsRed[4 * 64 + lane] +
                           ldsRed[8 * 64 + lane] + ldsRed[12 * 64 + lane];
                f32x4 tR = ldsRed[1 * 64 + lane] + ldsRed[5 * 64 + lane] +
                           ldsRed[9 * 64 + lane] + ldsRed[13 * 64 + lane];
                f32x4 tXH = ldsRed[2 * 64 + lane] + ldsRed[6 * 64 + lane] +
                            ldsRed[10 * 64 + lane] + ldsRed[14 * 64 + lane];
                f32x4 tRH = ldsRed[3 * 64 + lane] + ldsRed[7 * 64 + lane] +
                            ldsRed[11 * 64 + lane] + ldsRed[15 * 64 + lane];
#pragma unroll
                for (int i = 0; i < 4; ++i) {
                    const int brow = rowbase + quad * 4 + i;
                    float z = sigmf(tZ[i] + bzz);
                    float r = sigmf(tR[i] + brr);
                    float hh = tanhfast(tXH[i] + bxh + r * (tRH[i] + brh));
                    float hn = z * hcur[i] + (1.f - z) * hh;
                    hcur[i] = hn;
                    hseq[((size_t)brow * NSLOT + (t + 1)) * UU + u_] = f2bf(hn);
                    if (l == 2 && t == TT - 1) hfinal[brow * UU + u_] = hn;
                }
            }
            gridbar(bar, ++nbar);
        }
    }
}

// ---------------------------------------------------------------------------
// K4: logits = s.reshape(64,4,256) @ Wd[256,512] + bd; softmax over V=512.
// One WG per (b,f). hfinal is fp32.
// ---------------------------------------------------------------------------
__global__ __launch_bounds__(256, 1) void dense_softmax(
    const float* __restrict__ hfinal, const float* __restrict__ Wd,
    const float* __restrict__ bd, float* __restrict__ out)
{
    const int tid = threadIdx.x;
    const int bf = blockIdx.x;            // b*4 + f
    __shared__ float sv[256];
    __shared__ float red[256];
    sv[tid] = hfinal[bf * 256 + tid];     // b*1024 + f*256 + d == bf*256 + d
    __syncthreads();
    float a0 = bd[tid], a1 = bd[tid + 256];
    for (int d = 0; d < 256; ++d) {
        float s = sv[d];
        a0 = fmaf(s, Wd[d * 512 + tid], a0);
        a1 = fmaf(s, Wd[d * 512 + tid + 256], a1);
    }
    red[tid] = fmaxf(a0, a1);
    __syncthreads();
    for (int st = 128; st > 0; st >>= 1) {
        if (tid < st) red[tid] = fmaxf(red[tid], red[tid + st]);
        __syncthreads();
    }
    const float mx = red[0];
    __syncthreads();
    float e0 = __expf(a0 - mx), e1 = __expf(a1 - mx);
    red[tid] = e0 + e1;
    __syncthreads();
    for (int st = 128; st > 0; st >>= 1) {
        if (tid < st) red[tid] += red[tid + st];
        __syncthreads();
    }
    const float inv = 1.f / red[0];
    out[(size_t)bf * 512 + tid] = e0 * inv;
    out[(size_t)bf * 512 + tid + 256] = e1 * inv;
}

// ---------------------------------------------------------------------------
extern "C" void kernel_launch(void* const* d_in, const int* in_sizes, int n_in,
                              void* d_out, int out_size, void* d_ws, size_t ws_size,
                              hipStream_t stream)
{
    (void)in_sizes; (void)n_in; (void)out_size; (void)ws_size;

    const int*   tokens = (const int*)d_in[0];
    const float* emb    = (const float*)d_in[1];
    const float* gamma  = (const float*)d_in[2];
    const float* beta   = (const float*)d_in[3];
    const float* mean   = (const float*)d_in[4];
    const float* var    = (const float*)d_in[5];
    const float* g0k = (const float*)d_in[6];
    const float* g0r = (const float*)d_in[7];
    const float* g0b = (const float*)d_in[8];
    const float* g1k = (const float*)d_in[9];
    const float* g1r = (const float*)d_in[10];
    const float* g1b = (const float*)d_in[11];
    const float* g2k = (const float*)d_in[12];
    const float* g2r = (const float*)d_in[13];
    const float* g2b = (const float*)d_in[14];
    const float* dw  = (const float*)d_in[15];
    const float* db  = (const float*)d_in[16];

    // workspace carve (~168.5 MB)
    char* p = (char*)d_ws;
    ushort_t* seqA  = (ushort_t*)p; p += (size_t)BB * NSLOT * UU * 2;   // 67.24 MB
    ushort_t* seqB  = (ushort_t*)p; p += (size_t)BB * NSLOT * UU * 2;   // 67.24 MB
    ushort_t* embBN = (ushort_t*)p; p += (size_t)512 * 256 * 2;         // 256 KB
    ushort_t* WT0   = (ushort_t*)p; p += (size_t)3072 * 1280 * 2;       // 7.86 MB
    ushort_t* WT1   = (ushort_t*)p; p += (size_t)3072 * 2048 * 2;       // 12.58 MB
    ushort_t* WT2   = (ushort_t*)p; p += (size_t)3072 * 2048 * 2;       // 12.58 MB
    float*    hfin  = (float*)p;    p += (size_t)BB * UU * 4;           // 256 KB
    unsigned* bar   = (unsigned*)p; p += 4096;

    hipMemsetAsync(bar, 0, 4096, stream);

    pack_weights<<<dim3(1280 / 64, 48), 256, 0, stream>>>(g0k, g0r, WT0, 256, 1280);
    pack_weights<<<dim3(2048 / 64, 48), 256, 0, stream>>>(g1k, g1r, WT1, 1024, 2048);
    pack_weights<<<dim3(2048 / 64, 48), 256, 0, stream>>>(g2k, g2r, WT2, 1024, 2048);

    embed_bn<<<(512 * 256 + 64 * 1024 + 255) / 256, 256, 0, stream>>>(
        emb, gamma, beta, mean, var, embBN, seqA);

    gru_persistent<<<NWG, 256, 0, stream>>>(
        tokens, embBN, seqA, seqB, WT0, WT1, WT2, g0b, g1b, g2b, hfin, bar);

    dense_softmax<<<256, 256, 0, stream>>>(hfin, dw, db, (float*)d_out);
}

// Round 2
// 13836.633 us; speedup vs baseline: 5.1145x; 5.1145x over previous
//
#include <hip/hip_runtime.h>

// ---------------------------------------------------------------------------
// Teacher_model_7464653160858: embed+BN -> 3x GRU(1024, reset_after) -> dense+softmax
// B=64, T=512, E=256, U=1024, V=512.
//
// R2 design: NO __threadfence (R1: agent fences = full L2 wb/inv per step,
// 46us/step). Input projections precomputed as parallel GEMMs (T-chunked,
// TC=128). Serial path = h@Wr only (K=1024): 64 persistent-ish WGs per chunk,
// Wr B-frags register-resident, h exchanged through MALL via relaxed
// agent-scope atomics (sc0 sc1, no cache maintenance), two-level atomic
// barrier ordered by __syncthreads' vmcnt(0) drain. Phase coherence via
// kernel-launch boundaries.
// ---------------------------------------------------------------------------

typedef short bf16x8 __attribute__((ext_vector_type(8)));
typedef float f32x4 __attribute__((ext_vector_type(4)));
typedef unsigned short ushort_t;
typedef unsigned long long ull;

#define MFMA16(a, b, c) __builtin_amdgcn_mfma_f32_16x16x32_bf16((a), (b), (c), 0, 0, 0)

#define TC 128           // T-chunk for xproj buffer

__device__ __forceinline__ float bf2f(ushort_t h) {
    return __uint_as_float(((unsigned)h) << 16);
}
__device__ __forceinline__ ushort_t f2bf(float f) {
    unsigned u = __float_as_uint(f);
    u += 0x7FFFu + ((u >> 16) & 1u);   // RNE
    return (ushort_t)(u >> 16);
}
__device__ __forceinline__ float sigmf(float x) { return 1.f / (1.f + __expf(-x)); }
__device__ __forceinline__ float tanhfast(float x) {
    float e = __expf(2.f * x);
    return 1.f - 2.f / (e + 1.f);
}
__device__ __forceinline__ ull aload(const ull* p) {
    return __hip_atomic_load(p, __ATOMIC_RELAXED, __HIP_MEMORY_SCOPE_AGENT);
}
__device__ __forceinline__ void astore(unsigned* p, unsigned v) {
    __hip_atomic_store(p, v, __ATOMIC_RELAXED, __HIP_MEMORY_SCOPE_AGENT);
}

// ---------------------------------------------------------------------------
// pack: W[K][3072] fp32 -> WT[3072][K] bf16 (transpose). grid (K/64, 48).
// ---------------------------------------------------------------------------
__global__ __launch_bounds__(256, 1) void pack_w(
    const float* __restrict__ W, ushort_t* __restrict__ WT, int K)
{
    __shared__ ushort_t tile[64][72];
    const int kt0 = blockIdx.x * 64;
    const int ct0 = blockIdx.y * 64;
    const int tx = threadIdx.x & 63;
    const int ty = threadIdx.x >> 6;
#pragma unroll
    for (int i = 0; i < 16; ++i) {
        int k = kt0 + ty * 16 + i;
        tile[ty * 16 + i][tx] = f2bf(W[(size_t)k * 3072 + ct0 + tx]);
    }
    __syncthreads();
#pragma unroll
    for (int i = 0; i < 16; ++i) {
        int c = ct0 + ty * 16 + i;
        WT[(size_t)c * K + kt0 + tx] = tile[tx][ty * 16 + i];
    }
}

// ---------------------------------------------------------------------------
// BN-folded embedding table (512x256 bf16)
// ---------------------------------------------------------------------------
__global__ __launch_bounds__(256, 1) void embed_bn(
    const float* __restrict__ emb,
    const float* __restrict__ gamma, const float* __restrict__ beta,
    const float* __restrict__ mean, const float* __restrict__ var,
    ushort_t* __restrict__ embBN)
{
    const int idx = blockIdx.x * 256 + threadIdx.x;
    const int e = idx & 255;
    const float sc = gamma[e] * rsqrtf(var[e] + 1e-3f);
    const float sh = beta[e] - mean[e] * sc;
    embBN[idx] = f2bf(fmaf(emb[idx], sc, sh));
}

// ---------------------------------------------------------------------------
// xp_gemm: xp[b*TC+s][3072] = A[row][K] @ WkT^T. 128x128 tile, BK=32.
// blockIdx.x = b (row tile == one batch row's 128 timesteps), .y = col tile.
// L0: A row = embBN[tokens[b*512+t0+s]] (K=256). L>0: A = seq[b][t0+s] (K=1024).
// ---------------------------------------------------------------------------
__global__ __launch_bounds__(256, 2) void xp_gemm(
    const ushort_t* __restrict__ Asrc, const int* __restrict__ tokens,
    const ushort_t* __restrict__ WkT, ushort_t* __restrict__ xp,
    int K, int t0)
{
    const int tid = threadIdx.x;
    const int b = blockIdx.x;
    const int cb = blockIdx.y * 128;
    const int lane = tid & 63, w = tid >> 6;
    const int n = lane & 15, quad = lane >> 4;
    __shared__ ushort_t sA[128 * 40], sB[128 * 40];   // +8 pad: 2-way banks

    const int m0 = tid >> 2, kq0 = (tid & 3) * 8;
    const int m1 = m0 + 64, kq1 = kq0;
    const ushort_t *ga0, *ga1;
    if (tokens) {
        ga0 = Asrc + (size_t)tokens[b * 512 + t0 + m0] * 256;
        ga1 = Asrc + (size_t)tokens[b * 512 + t0 + m1] * 256;
    } else {
        ga0 = Asrc + ((size_t)b * 512 + t0 + m0) * 1024;
        ga1 = Asrc + ((size_t)b * 512 + t0 + m1) * 1024;
    }
    const ushort_t* gb0 = WkT + (size_t)(cb + m0) * K;
    const ushort_t* gb1 = WkT + (size_t)(cb + m1) * K;

    f32x4 acc[4][4] = {};
    const int rw = (w & 1) * 64, cw = (w >> 1) * 64;

    for (int kb = 0; kb < K; kb += 32) {
        __syncthreads();
        *(bf16x8*)(sA + m0 * 40 + kq0) = *(const bf16x8*)(ga0 + kb + kq0);
        *(bf16x8*)(sA + m1 * 40 + kq1) = *(const bf16x8*)(ga1 + kb + kq1);
        *(bf16x8*)(sB + m0 * 40 + kq0) = *(const bf16x8*)(gb0 + kb + kq0);
        *(bf16x8*)(sB + m1 * 40 + kq1) = *(const bf16x8*)(gb1 + kb + kq1);
        __syncthreads();
        bf16x8 Af[4], Bf[4];
#pragma unroll
        for (int rt = 0; rt < 4; ++rt)
            Af[rt] = *(const bf16x8*)(sA + (rw + rt * 16 + n) * 40 + quad * 8);
#pragma unroll
        for (int nt = 0; nt < 4; ++nt)
            Bf[nt] = *(const bf16x8*)(sB + (cw + nt * 16 + n) * 40 + quad * 8);
#pragma unroll
        for (int rt = 0; rt < 4; ++rt)
#pragma unroll
            for (int nt = 0; nt < 4; ++nt)
                acc[rt][nt] = MFMA16(Af[rt], Bf[nt], acc[rt][nt]);
    }
    // epilogue: pack col pairs, dword stores
#pragma unroll
    for (int rt = 0; rt < 4; ++rt)
#pragma unroll
        for (int nt = 0; nt < 4; ++nt)
#pragma unroll
            for (int reg = 0; reg < 4; ++reg) {
                float v = acc[rt][nt][reg];
                float v2 = __shfl_xor(v, 1);
                if ((lane & 1) == 0) {
                    int row = rw + rt * 16 + quad * 4 + reg;
                    int col = cb + cw + nt * 16 + n;
                    unsigned pk = (unsigned)f2bf(v) | ((unsigned)f2bf(v2) << 16);
                    *(unsigned*)(xp + ((size_t)b * TC + row) * 3072 + col) = pk;
                }
            }
}

// ---------------------------------------------------------------------------
// gru_seq: one T-chunk of one layer's recurrence. 64 WGs x 256 thr.
// WG g owns u in [g*16, g*16+16) (48 gate cols). Waves: w = kh*2+rh:
// kh = K-half (512), rh = row-half (32 batch rows). Wr frags in registers.
// h exchange: HxP layout [kc 32][qq 8][b 64][4 elems] bf16, 2 parity slots,
// relaxed agent atomics. Barrier: 8 groups x 8 WGs -> root, relaxed atomics.
// ---------------------------------------------------------------------------
__global__ __launch_bounds__(256, 1) void gru_seq(
    const ushort_t* __restrict__ xp,    // [64*TC][3072]
    const ushort_t* __restrict__ WrT,   // [3072][1024]
    const float* __restrict__ gb,       // [2][3072] flat
    ushort_t* __restrict__ seq,         // [64][512][1024]
    ushort_t* __restrict__ Hx,          // 2 slots x [64*1024] (HxP layout)
    float* __restrict__ Hf,             // [64][1024] fp32 carry
    unsigned* __restrict__ bar,
    int t0, int first, int writeSeq)
{
    const int tid = threadIdx.x;
    const int wg = blockIdx.x;                // 0..63
    const int lane = tid & 63;
    const int w = tid >> 6;
    const int kh = w >> 1, rh = w & 1;
    const int n = lane & 15, quad = lane >> 4;
    const int u_ = wg * 16 + n;
    const int rt0 = rh * 2;

    __shared__ f32x4 ldsRed[2 * 6 * 64];      // [rh][rt2*3+g][lane], 12 KB

    // ---- Wr B-frags register-resident: [kc 16][g 3], this wave's K-half ----
    bf16x8 Bf[16][3];
#pragma unroll
    for (int kc = 0; kc < 16; ++kc) {
        int k = (kh * 16 + kc) * 32 + quad * 8;
#pragma unroll
        for (int g = 0; g < 3; ++g)
            Bf[kc][g] = *(const bf16x8*)(WrT + (size_t)(g * 1024 + u_) * 1024 + k);
    }

    const float bzz = gb[u_] + gb[3072 + u_];
    const float brr = gb[1024 + u_] + gb[3072 + 1024 + u_];
    const float bxh = gb[2048 + u_];
    const float brh = gb[3072 + 2048 + u_];

    float hcur[8];                            // kh==0 waves: [rtl*4+i]
    if (kh == 0) {
#pragma unroll
        for (int j = 0; j < 8; ++j) {
            int b = (rt0 + (j >> 2)) * 16 + quad * 4 + (j & 3);
            hcur[j] = first ? 0.f : Hf[b * 1024 + u_];
        }
    }

    for (int s = 0; s < TC; ++s) {
        const int t = t0 + s;
        const ushort_t* hxR = Hx + (size_t)(t & 1) * 65536;
        ushort_t* hxW = (ushort_t*)Hx + (size_t)((t + 1) & 1) * 65536;

        // xp prefetch (kh==0 waves): [rtl][i][g]
        float xv[2][4][3];
        if (kh == 0) {
#pragma unroll
            for (int rtl = 0; rtl < 2; ++rtl)
#pragma unroll
                for (int i = 0; i < 4; ++i) {
                    int b = (rt0 + rtl) * 16 + quad * 4 + i;
                    const ushort_t* xr = xp + ((size_t)b * TC + s) * 3072 + u_;
#pragma unroll
                    for (int g = 0; g < 3; ++g)
                        xv[rtl][i][g] = bf2f(xr[g * 1024]);
                }
        }

        f32x4 acc[2][3] = {};
        if (!(first && s == 0)) {
            const ull* hb = (const ull*)hxR;
#pragma unroll
            for (int kc = 0; kc < 16; ++kc) {
                const int kcg = kh * 16 + kc;
                union { ull q[2]; bf16x8 v; } a0, a1;
                size_t i0 = (size_t)(kcg * 8 + quad * 2) * 64 + rt0 * 16 + n;
                size_t i1 = i0 + 16;          // (rt0+1)*16
                a0.q[0] = aload(hb + i0);
                a0.q[1] = aload(hb + i0 + 64);
                a1.q[0] = aload(hb + i1);
                a1.q[1] = aload(hb + i1 + 64);
#pragma unroll
                for (int g = 0; g < 3; ++g) {
                    acc[0][g] = MFMA16(a0.v, Bf[kc][g], acc[0][g]);
                    acc[1][g] = MFMA16(a1.v, Bf[kc][g], acc[1][g]);
                }
            }
        }

        // cross-wave K-reduce: kh1 -> LDS -> kh0
        if (kh == 1) {
#pragma unroll
            for (int rtl = 0; rtl < 2; ++rtl)
#pragma unroll
                for (int g = 0; g < 3; ++g)
                    ldsRed[((rh * 2 + rtl) * 3 + g) * 64 + lane] = acc[rtl][g];
        }
        __syncthreads();

        if (kh == 0) {
#pragma unroll
            for (int rtl = 0; rtl < 2; ++rtl) {
#pragma unroll
                for (int g = 0; g < 3; ++g)
                    acc[rtl][g] += ldsRed[((rh * 2 + rtl) * 3 + g) * 64 + lane];
#pragma unroll
                for (int i = 0; i < 4; ++i) {
                    float z = sigmf(acc[rtl][0][i] + xv[rtl][i][0] + bzz);
                    float r = sigmf(acc[rtl][1][i] + xv[rtl][i][1] + brr);
                    float hh = tanhfast(acc[rtl][2][i] + xv[rtl][i][2] + bxh +
                                        r * (acc[rtl][2][i] * 0.f + acc[rtl][2][i] * 0.f +
                                             acc[rtl][2][i] - acc[rtl][2][i] + acc[rtl][2][i] + brh) -
                                        (acc[rtl][2][i] + 0.f));
                    // NOTE: expression above must be hh = tanh(xh + bxh + r*(rh_rec + brh));
                    // rewritten cleanly below (kept single assignment for clarity):
                    hh = tanhfast(xv[rtl][i][2] + bxh + r * (acc[rtl][2][i] + brh));
                    float hn = z * hcur[rtl * 4 + i] + (1.f - z) * hh;
                    hcur[rtl * 4 + i] = hn;
                    float hn2 = __shfl_xor(hn, 1);
                    if ((lane & 1) == 0) {
                        unsigned pk = (unsigned)f2bf(hn) | ((unsigned)f2bf(hn2) << 16);
                        int b = (rt0 + rtl) * 16 + quad * 4 + i;
                        size_t fe = ((size_t)((u_ >> 5) * 8 + ((u_ >> 2) & 7)) * 64 + b) * 4 + (u_ & 3);
                        astore((unsigned*)hxW + (fe >> 1), pk);
                        if (writeSeq)
                            *(unsigned*)(seq + ((size_t)b * 512 + t) * 1024 + u_) = pk;
                    }
                }
            }
        }

        // grid barrier (skip after last step; kernel end syncs)
        if (s < TC - 1) {
            __syncthreads();                  // drains vmcnt(0): h stores visible at MALL
            if (tid == 0) {
                const unsigned g = wg >> 3;
                unsigned old = __hip_atomic_fetch_add(&bar[g * 32], 1u,
                                   __ATOMIC_RELAXED, __HIP_MEMORY_SCOPE_AGENT);
                if (old + 1u == 8u * (unsigned)(s + 1))
                    __hip_atomic_fetch_add(&bar[512], 1u,
                        __ATOMIC_RELAXED, __HIP_MEMORY_SCOPE_AGENT);
                while (__hip_atomic_load(&bar[512], __ATOMIC_RELAXED,
                                         __HIP_MEMORY_SCOPE_AGENT) < 8u * (unsigned)(s + 1))
                    __builtin_amdgcn_s_sleep(2);
            }
            __syncthreads();
        }
    }

    if (kh == 0) {
#pragma unroll
        for (int j = 0; j < 8; ++j) {
            int b = (rt0 + (j >> 2)) * 16 + quad * 4 + (j & 3);
            Hf[b * 1024 + u_] = hcur[j];
        }
    }
}

// ---------------------------------------------------------------------------
// dense + softmax (verified in R1). One WG per (b,f).
// ---------------------------------------------------------------------------
__global__ __launch_bounds__(256, 1) void dense_softmax(
    const float* __restrict__ hfinal, const float* __restrict__ Wd,
    const float* __restrict__ bd, float* __restrict__ out)
{
    const int tid = threadIdx.x;
    const int bf = blockIdx.x;
    __shared__ float sv[256];
    __shared__ float red[256];
    sv[tid] = hfinal[bf * 256 + tid];
    __syncthreads();
    float a0 = bd[tid], a1 = bd[tid + 256];
    for (int d = 0; d < 256; ++d) {
        float s = sv[d];
        a0 = fmaf(s, Wd[d * 512 + tid], a0);
        a1 = fmaf(s, Wd[d * 512 + tid + 256], a1);
    }
    red[tid] = fmaxf(a0, a1);
    __syncthreads();
    for (int st = 128; st > 0; st >>= 1) {
        if (tid < st) red[tid] = fmaxf(red[tid], red[tid + st]);
        __syncthreads();
    }
    const float mx = red[0];
    __syncthreads();
    float e0 = __expf(a0 - mx), e1 = __expf(a1 - mx);
    red[tid] = e0 + e1;
    __syncthreads();
    for (int st = 128; st > 0; st >>= 1) {
        if (tid < st) red[tid] += red[tid + st];
        __syncthreads();
    }
    const float inv = 1.f / red[0];
    out[(size_t)bf * 512 + tid] = e0 * inv;
    out[(size_t)bf * 512 + tid + 256] = e1 * inv;
}

// ---------------------------------------------------------------------------
extern "C" void kernel_launch(void* const* d_in, const int* in_sizes, int n_in,
                              void* d_out, int out_size, void* d_ws, size_t ws_size,
                              hipStream_t stream)
{
    (void)in_sizes; (void)n_in; (void)out_size; (void)ws_size;

    const int*   tokens = (const int*)d_in[0];
    const float* emb    = (const float*)d_in[1];
    const float* gamma  = (const float*)d_in[2];
    const float* beta   = (const float*)d_in[3];
    const float* mean   = (const float*)d_in[4];
    const float* var    = (const float*)d_in[5];
    const float* gk[3]  = {(const float*)d_in[6], (const float*)d_in[9],  (const float*)d_in[12]};
    const float* gr[3]  = {(const float*)d_in[7], (const float*)d_in[10], (const float*)d_in[13]};
    const float* gbb[3] = {(const float*)d_in[8], (const float*)d_in[11], (const float*)d_in[14]};
    const float* dw  = (const float*)d_in[15];
    const float* db  = (const float*)d_in[16];

    // workspace carve (~151.4 MB)
    char* p = (char*)d_ws;
    ushort_t* seq   = (ushort_t*)p; p += (size_t)64 * 512 * 1024 * 2;   // 67.1 MB
    ushort_t* xp    = (ushort_t*)p; p += (size_t)64 * TC * 3072 * 2;    // 50.3 MB
    ushort_t* WkT0  = (ushort_t*)p; p += (size_t)3072 * 256 * 2;        // 1.57 MB
    ushort_t* WkT1  = (ushort_t*)p; p += (size_t)3072 * 1024 * 2;       // 6.29 MB
    ushort_t* WkT2  = (ushort_t*)p; p += (size_t)3072 * 1024 * 2;
    ushort_t* WrT[3];
    for (int l = 0; l < 3; ++l) { WrT[l] = (ushort_t*)p; p += (size_t)3072 * 1024 * 2; }
    ushort_t* embBN = (ushort_t*)p; p += (size_t)512 * 256 * 2;         // 256 KB
    ushort_t* Hx    = (ushort_t*)p; p += (size_t)2 * 64 * 1024 * 2;     // 256 KB
    float*    Hf    = (float*)p;    p += (size_t)64 * 1024 * 4;         // 256 KB
    unsigned* bar   = (unsigned*)p; p += 12 * 4096;

    hipMemsetAsync(bar, 0, 12 * 4096, stream);

    pack_w<<<dim3(4, 48),  256, 0, stream>>>(gk[0], WkT0, 256);
    pack_w<<<dim3(16, 48), 256, 0, stream>>>(gk[1], WkT1, 1024);
    pack_w<<<dim3(16, 48), 256, 0, stream>>>(gk[2], WkT2, 1024);
    for (int l = 0; l < 3; ++l)
        pack_w<<<dim3(16, 48), 256, 0, stream>>>(gr[l], WrT[l], 1024);

    embed_bn<<<512, 256, 0, stream>>>(emb, gamma, beta, mean, var, embBN);

    const ushort_t* WkTl[3] = {WkT0, WkT1, WkT2};
    for (int L = 0; L < 3; ++L) {
        for (int c = 0; c < 4; ++c) {
            const int t0 = c * TC;
            if (L == 0)
                xp_gemm<<<dim3(64, 24), 256, 0, stream>>>(embBN, tokens, WkTl[0], xp, 256, t0);
            else
                xp_gemm<<<dim3(64, 24), 256, 0, stream>>>(seq, nullptr, WkTl[L], xp, 1024, t0);
            gru_seq<<<64, 256, 0, stream>>>(
                xp, WrT[L], gbb[L], seq, Hx, Hf,
                bar + (size_t)(L * 4 + c) * 1024, t0,
                (L == 0 && c == 0) ? 1 : 0, (L < 2) ? 1 : 0);
        }
    }

    dense_softmax<<<256, 256, 0, stream>>>(Hf, dw, db, (float*)d_out);
}

// Round 3
// 11784.371 us; speedup vs baseline: 6.0052x; 1.1742x over previous
//
#include <hip/hip_runtime.h>

// ---------------------------------------------------------------------------
// Teacher_model_7464653160858: embed+BN -> 3x GRU(1024, reset_after) -> dense+softmax
// B=64, T=512, E=256, U=1024, V=512.
//
// R3: serial path = h@Wr (K=1024) on 64 WGs.
//  - Wr slice (96KB) staged in LDS once per dispatch (R2's VGPR_Count=172
//    proved the compiler was re-loading "register" frags from L2 every step).
//  - h exchange: per-step unique slabs Hx[s][u8][b][8] bf16. Stores sc0sc1
//    (atomic, write-through to MALL); reads PLAIN (L2-cacheable - safe because
//    addresses are never reused intra-dispatch, kernel-entry __threadfence
//    drops stale/poisoned L2 lines, and reads are flag-gated).
//  - Barrier: flags[wg] = monotonic global step (memset 0 EVERY launch - the
//    0xAA ws poison would otherwise satisfy any poll). wave0 polls 64 flags
//    with one lane-parallel atomic load + ballot; no hot-line fetch_adds.
//  - xp loads hoisted to iteration top (consumed ~2000cy later at gating).
// ---------------------------------------------------------------------------

typedef short bf16x8 __attribute__((ext_vector_type(8)));
typedef float f32x4 __attribute__((ext_vector_type(4)));
typedef unsigned short ushort_t;

#define MFMA16(a, b, c) __builtin_amdgcn_mfma_f32_16x16x32_bf16((a), (b), (c), 0, 0, 0)

#define TC 128            // T-chunk
#define SLAB 65536        // elems per h slab: 128 u8-groups * 64 b * 8

__device__ __forceinline__ float bf2f(ushort_t h) {
    return __uint_as_float(((unsigned)h) << 16);
}
__device__ __forceinline__ ushort_t f2bf(float f) {
    unsigned u = __float_as_uint(f);
    u += 0x7FFFu + ((u >> 16) & 1u);   // RNE
    return (ushort_t)(u >> 16);
}
__device__ __forceinline__ float sigmf(float x) { return 1.f / (1.f + __expf(-x)); }
__device__ __forceinline__ float tanhfast(float x) {
    float e = __expf(2.f * x);
    return 1.f - 2.f / (e + 1.f);
}

// ---------------------------------------------------------------------------
// pack: W[K][3072] fp32 -> WT[3072][K] bf16 (transpose). grid (K/64, 48).
// ---------------------------------------------------------------------------
__global__ __launch_bounds__(256, 1) void pack_w(
    const float* __restrict__ W, ushort_t* __restrict__ WT, int K)
{
    __shared__ ushort_t tile[64][72];
    const int kt0 = blockIdx.x * 64;
    const int ct0 = blockIdx.y * 64;
    const int tx = threadIdx.x & 63;
    const int ty = threadIdx.x >> 6;
#pragma unroll
    for (int i = 0; i < 16; ++i) {
        int k = kt0 + ty * 16 + i;
        tile[ty * 16 + i][tx] = f2bf(W[(size_t)k * 3072 + ct0 + tx]);
    }
    __syncthreads();
#pragma unroll
    for (int i = 0; i < 16; ++i) {
        int c = ct0 + ty * 16 + i;
        WT[(size_t)c * K + kt0 + tx] = tile[tx][ty * 16 + i];
    }
}

// ---------------------------------------------------------------------------
// BN-folded embedding table (512x256 bf16)
// ---------------------------------------------------------------------------
__global__ __launch_bounds__(256, 1) void embed_bn(
    const float* __restrict__ emb,
    const float* __restrict__ gamma, const float* __restrict__ beta,
    const float* __restrict__ mean, const float* __restrict__ var,
    ushort_t* __restrict__ embBN)
{
    const int idx = blockIdx.x * 256 + threadIdx.x;
    const int e = idx & 255;
    const float sc = gamma[e] * rsqrtf(var[e] + 1e-3f);
    const float sh = beta[e] - mean[e] * sc;
    embBN[idx] = f2bf(fmaf(emb[idx], sc, sh));
}

// ---------------------------------------------------------------------------
// xp_gemm (unchanged from R2, verified): xp[b*TC+s][3072] = A @ WkT^T.
// ---------------------------------------------------------------------------
__global__ __launch_bounds__(256, 2) void xp_gemm(
    const ushort_t* __restrict__ Asrc, const int* __restrict__ tokens,
    const ushort_t* __restrict__ WkT, ushort_t* __restrict__ xp,
    int K, int t0)
{
    const int tid = threadIdx.x;
    const int b = blockIdx.x;
    const int cb = blockIdx.y * 128;
    const int lane = tid & 63, w = tid >> 6;
    const int n = lane & 15, quad = lane >> 4;
    __shared__ ushort_t sA[128 * 40], sB[128 * 40];

    const int m0 = tid >> 2, kq0 = (tid & 3) * 8;
    const int m1 = m0 + 64;
    const ushort_t *ga0, *ga1;
    if (tokens) {
        ga0 = Asrc + (size_t)tokens[b * 512 + t0 + m0] * 256;
        ga1 = Asrc + (size_t)tokens[b * 512 + t0 + m1] * 256;
    } else {
        ga0 = Asrc + ((size_t)b * 512 + t0 + m0) * 1024;
        ga1 = Asrc + ((size_t)b * 512 + t0 + m1) * 1024;
    }
    const ushort_t* gb0 = WkT + (size_t)(cb + m0) * K;
    const ushort_t* gb1 = WkT + (size_t)(cb + m1) * K;

    f32x4 acc[4][4] = {};
    const int rw = (w & 1) * 64, cw = (w >> 1) * 64;

    for (int kb = 0; kb < K; kb += 32) {
        __syncthreads();
        *(bf16x8*)(sA + m0 * 40 + kq0) = *(const bf16x8*)(ga0 + kb + kq0);
        *(bf16x8*)(sA + m1 * 40 + kq0) = *(const bf16x8*)(ga1 + kb + kq0);
        *(bf16x8*)(sB + m0 * 40 + kq0) = *(const bf16x8*)(gb0 + kb + kq0);
        *(bf16x8*)(sB + m1 * 40 + kq0) = *(const bf16x8*)(gb1 + kb + kq0);
        __syncthreads();
        bf16x8 Af[4], Bf[4];
#pragma unroll
        for (int rt = 0; rt < 4; ++rt)
            Af[rt] = *(const bf16x8*)(sA + (rw + rt * 16 + n) * 40 + quad * 8);
#pragma unroll
        for (int nt = 0; nt < 4; ++nt)
            Bf[nt] = *(const bf16x8*)(sB + (cw + nt * 16 + n) * 40 + quad * 8);
#pragma unroll
        for (int rt = 0; rt < 4; ++rt)
#pragma unroll
            for (int nt = 0; nt < 4; ++nt)
                acc[rt][nt] = MFMA16(Af[rt], Bf[nt], acc[rt][nt]);
    }
#pragma unroll
    for (int rt = 0; rt < 4; ++rt)
#pragma unroll
        for (int nt = 0; nt < 4; ++nt)
#pragma unroll
            for (int reg = 0; reg < 4; ++reg) {
                float v = acc[rt][nt][reg];
                float v2 = __shfl_xor(v, 1);
                if ((lane & 1) == 0) {
                    int row = rw + rt * 16 + quad * 4 + reg;
                    int col = cb + cw + nt * 16 + n;
                    unsigned pk = (unsigned)f2bf(v) | ((unsigned)f2bf(v2) << 16);
                    *(unsigned*)(xp + ((size_t)b * TC + row) * 3072 + col) = pk;
                }
            }
}

// ---------------------------------------------------------------------------
// gru_seq v3. 64 WGs x 256 thr. WG wg owns u in [wg*16, wg*16+16).
// waves: w = kh*2+rh. kh = K-half of h@Wr; rh = batch-row-half (32 rows).
// Wr slice in LDS (stride 1032 elems: bank-balanced b128 reads).
// ---------------------------------------------------------------------------
__global__ __launch_bounds__(256, 1) void gru_seq(
    const ushort_t* __restrict__ xp,    // [64*TC][3072]
    const ushort_t* __restrict__ WrT,   // [3072][1024]
    const float* __restrict__ gb,       // [2][3072] flat
    ushort_t* __restrict__ seq,         // [64][512][1024]
    ushort_t* __restrict__ Hx,          // [TC][SLAB] bf16
    float* __restrict__ Hf,             // [64][1024] fp32 carry
    unsigned* __restrict__ flags,       // [64], zeroed each launch
    int t0, int sBase, int first, int writeSeq)
{
    __shared__ ushort_t ldsW[48 * 1032];      // 99,072 B Wr slice
    __shared__ f32x4 ldsRed[12 * 64];         // 12,288 B K-reduce

    const int tid = threadIdx.x;
    const int wg = blockIdx.x;
    const int lane = tid & 63;
    const int w = tid >> 6;
    const int kh = w >> 1, rh = w & 1;
    const int n = lane & 15, quad = lane >> 4;
    const int u_ = wg * 16 + n;
    const int rt0 = rh * 2;

    // once per dispatch: drop stale/poisoned L2 lines (cheap at this frequency)
    __threadfence();

    // ---- stage Wr slice: row r = g*16+nn, k 0..1023, stride 1032 ----
    for (int idx = tid; idx < 48 * 128; idx += 256) {
        int r = idx >> 7, ko = (idx & 127) * 8;
        int g = r >> 4, nn = r & 15;
        *(bf16x8*)(ldsW + r * 1032 + ko) =
            *(const bf16x8*)(WrT + ((size_t)(g * 1024 + wg * 16 + nn)) * 1024 + ko);
    }

    const float bzz = gb[u_] + gb[3072 + u_];
    const float brr = gb[1024 + u_] + gb[3072 + 1024 + u_];
    const float bxh = gb[2048 + u_];
    const float brh = gb[3072 + 2048 + u_];

    float hcur[8];                            // kh==0 waves only
    if (kh == 0) {
#pragma unroll
        for (int j = 0; j < 8; ++j) {
            int b = (rt0 + (j >> 2)) * 16 + quad * 4 + (j & 3);
            hcur[j] = first ? 0.f : Hf[b * 1024 + u_];
        }
    }
    __syncthreads();                          // ldsW ready

    for (int s = 0; s < TC; ++s) {
        const int t = t0 + s;

        // 1. xp prefetch (kh0 waves) - consumed at gating, ~2000cy later
        float xv[2][4][3];
        if (kh == 0) {
#pragma unroll
            for (int rtl = 0; rtl < 2; ++rtl)
#pragma unroll
                for (int i = 0; i < 4; ++i) {
                    int b = (rt0 + rtl) * 16 + quad * 4 + i;
                    const ushort_t* xr = xp + ((size_t)b * TC + s) * 3072 + u_;
#pragma unroll
                    for (int g = 0; g < 3; ++g)
                        xv[rtl][i][g] = bf2f(xr[g * 1024]);
                }
        }

        // 2. wave0 polls: h_{t-1} published by all 64 WGs?
        if (w == 0) {
            const unsigned target = (unsigned)(sBase + s);
            if (target) {
                while (true) {
                    unsigned f = __hip_atomic_load(flags + lane, __ATOMIC_RELAXED,
                                                   __HIP_MEMORY_SCOPE_AGENT);
                    if (__ballot(f >= target) == ~0ull) break;
                    __builtin_amdgcn_s_sleep(1);
                }
            }
        }
        __syncthreads();
        asm volatile("" ::: "memory");        // no load hoisting above the poll

        // 3. h plain loads (L2-cacheable; fresh addresses) + MFMA
        f32x4 acc[2][3] = {};
        if (!(first && s == 0)) {
            const ushort_t* slab = Hx + (size_t)((s + TC - 1) & (TC - 1)) * SLAB;
#pragma unroll
            for (int kc = 0; kc < 16; ++kc) {
                const int kcg = kh * 16 + kc;
                const ushort_t* hb = slab + (size_t)((kcg * 4 + quad) * 64) * 8;
                bf16x8 a0 = *(const bf16x8*)(hb + (rt0 * 16 + n) * 8);
                bf16x8 a1 = *(const bf16x8*)(hb + (rt0 * 16 + 16 + n) * 8);
#pragma unroll
                for (int g = 0; g < 3; ++g) {
                    bf16x8 bfr = *(const bf16x8*)(ldsW + (size_t)(g * 16 + n) * 1032 +
                                                  kcg * 32 + quad * 8);
                    acc[0][g] = MFMA16(a0, bfr, acc[0][g]);
                    acc[1][g] = MFMA16(a1, bfr, acc[1][g]);
                }
            }
        }

        // 4. cross-wave K-reduce: kh1 -> LDS -> kh0
        if (kh == 1) {
#pragma unroll
            for (int rtl = 0; rtl < 2; ++rtl)
#pragma unroll
                for (int g = 0; g < 3; ++g)
                    ldsRed[((rh * 2 + rtl) * 3 + g) * 64 + lane] = acc[rtl][g];
        }
        __syncthreads();

        // 5. gating + publish h_t (kh0 waves)
        if (kh == 0) {
            ushort_t* hxW = (ushort_t*)Hx + (size_t)(s & (TC - 1)) * SLAB;
#pragma unroll
            for (int rtl = 0; rtl < 2; ++rtl) {
#pragma unroll
                for (int g = 0; g < 3; ++g)
                    acc[rtl][g] += ldsRed[((rh * 2 + rtl) * 3 + g) * 64 + lane];
#pragma unroll
                for (int i = 0; i < 4; ++i) {
                    float z = sigmf(acc[rtl][0][i] + xv[rtl][i][0] + bzz);
                    float r = sigmf(acc[rtl][1][i] + xv[rtl][i][1] + brr);
                    float hh = tanhfast(xv[rtl][i][2] + bxh + r * (acc[rtl][2][i] + brh));
                    float hn = z * hcur[rtl * 4 + i] + (1.f - z) * hh;
                    hcur[rtl * 4 + i] = hn;
                    float hn2 = __shfl_xor(hn, 1);
                    if ((lane & 1) == 0) {
                        unsigned pk = (unsigned)f2bf(hn) | ((unsigned)f2bf(hn2) << 16);
                        int b = (rt0 + rtl) * 16 + quad * 4 + i;
                        size_t e = ((size_t)(u_ >> 3) * 64 + b) * 8 + (u_ & 7);
                        __hip_atomic_store((unsigned*)hxW + (e >> 1), pk,
                                           __ATOMIC_RELAXED, __HIP_MEMORY_SCOPE_AGENT);
                        if (writeSeq)
                            *(unsigned*)(seq + ((size_t)b * 512 + t) * 1024 + u_) = pk;
                    }
                }
            }
        }

        // 6. drain (syncthreads waits each thread's own vmcnt) then publish flag
        __syncthreads();
        if (tid == 0)
            __hip_atomic_store(flags + wg, (unsigned)(sBase + s + 1),
                               __ATOMIC_RELAXED, __HIP_MEMORY_SCOPE_AGENT);
    }

    if (kh == 0) {
#pragma unroll
        for (int j = 0; j < 8; ++j) {
            int b = (rt0 + (j >> 2)) * 16 + quad * 4 + (j & 3);
            Hf[b * 1024 + u_] = hcur[j];
        }
    }
}

// ---------------------------------------------------------------------------
// dense + softmax (verified). One WG per (b,f).
// ---------------------------------------------------------------------------
__global__ __launch_bounds__(256, 1) void dense_softmax(
    const float* __restrict__ hfinal, const float* __restrict__ Wd,
    const float* __restrict__ bd, float* __restrict__ out)
{
    const int tid = threadIdx.x;
    const int bf = blockIdx.x;
    __shared__ float sv[256];
    __shared__ float red[256];
    sv[tid] = hfinal[bf * 256 + tid];
    __syncthreads();
    float a0 = bd[tid], a1 = bd[tid + 256];
    for (int d = 0; d < 256; ++d) {
        float s = sv[d];
        a0 = fmaf(s, Wd[d * 512 + tid], a0);
        a1 = fmaf(s, Wd[d * 512 + tid + 256], a1);
    }
    red[tid] = fmaxf(a0, a1);
    __syncthreads();
    for (int st = 128; st > 0; st >>= 1) {
        if (tid < st) red[tid] = fmaxf(red[tid], red[tid + st]);
        __syncthreads();
    }
    const float mx = red[0];
    __syncthreads();
    float e0 = __expf(a0 - mx), e1 = __expf(a1 - mx);
    red[tid] = e0 + e1;
    __syncthreads();
    for (int st = 128; st > 0; st >>= 1) {
        if (tid < st) red[tid] += red[tid + st];
        __syncthreads();
    }
    const float inv = 1.f / red[0];
    out[(size_t)bf * 512 + tid] = e0 * inv;
    out[(size_t)bf * 512 + tid + 256] = e1 * inv;
}

// ---------------------------------------------------------------------------
extern "C" void kernel_launch(void* const* d_in, const int* in_sizes, int n_in,
                              void* d_out, int out_size, void* d_ws, size_t ws_size,
                              hipStream_t stream)
{
    (void)in_sizes; (void)n_in; (void)out_size; (void)ws_size;

    const int*   tokens = (const int*)d_in[0];
    const float* emb    = (const float*)d_in[1];
    const float* gamma  = (const float*)d_in[2];
    const float* beta   = (const float*)d_in[3];
    const float* mean   = (const float*)d_in[4];
    const float* var    = (const float*)d_in[5];
    const float* gk[3]  = {(const float*)d_in[6], (const float*)d_in[9],  (const float*)d_in[12]};
    const float* gr[3]  = {(const float*)d_in[7], (const float*)d_in[10], (const float*)d_in[13]};
    const float* gbb[3] = {(const float*)d_in[8], (const float*)d_in[11], (const float*)d_in[14]};
    const float* dw  = (const float*)d_in[15];
    const float* db  = (const float*)d_in[16];

    // workspace carve (~167.8 MB)
    char* p = (char*)d_ws;
    ushort_t* seq   = (ushort_t*)p; p += (size_t)64 * 512 * 1024 * 2;   // 67.1 MB
    ushort_t* xp    = (ushort_t*)p; p += (size_t)64 * TC * 3072 * 2;    // 50.3 MB
    ushort_t* WkT0  = (ushort_t*)p; p += (size_t)3072 * 256 * 2;
    ushort_t* WkT1  = (ushort_t*)p; p += (size_t)3072 * 1024 * 2;
    ushort_t* WkT2  = (ushort_t*)p; p += (size_t)3072 * 1024 * 2;
    ushort_t* WrT[3];
    for (int l = 0; l < 3; ++l) { WrT[l] = (ushort_t*)p; p += (size_t)3072 * 1024 * 2; }
    ushort_t* embBN = (ushort_t*)p; p += (size_t)512 * 256 * 2;
    ushort_t* Hx    = (ushort_t*)p; p += (size_t)TC * SLAB * 2;         // 16.8 MB
    float*    Hf    = (float*)p;    p += (size_t)64 * 1024 * 4;
    unsigned* flags = (unsigned*)p; p += 4096;

    // MUST zero every launch: 0xAA ws poison would satisfy every flag poll.
    hipMemsetAsync(flags, 0, 4096, stream);

    pack_w<<<dim3(4, 48),  256, 0, stream>>>(gk[0], WkT0, 256);
    pack_w<<<dim3(16, 48), 256, 0, stream>>>(gk[1], WkT1, 1024);
    pack_w<<<dim3(16, 48), 256, 0, stream>>>(gk[2], WkT2, 1024);
    for (int l = 0; l < 3; ++l)
        pack_w<<<dim3(16, 48), 256, 0, stream>>>(gr[l], WrT[l], 1024);

    embed_bn<<<512, 256, 0, stream>>>(emb, gamma, beta, mean, var, embBN);

    const ushort_t* WkTl[3] = {WkT0, WkT1, WkT2};
    int dIdx = 0;
    for (int L = 0; L < 3; ++L) {
        for (int c = 0; c < 4; ++c) {
            const int t0 = c * TC;
            if (L == 0)
                xp_gemm<<<dim3(64, 24), 256, 0, stream>>>(embBN, tokens, WkTl[0], xp, 256, t0);
            else
                xp_gemm<<<dim3(64, 24), 256, 0, stream>>>(seq, nullptr, WkTl[L], xp, 1024, t0);
            gru_seq<<<64, 256, 0, stream>>>(
                xp, WrT[L], gbb[L], seq, Hx, Hf, flags,
                t0, dIdx * TC, (dIdx == 0) ? 1 : 0, (L < 2) ? 1 : 0);
            ++dIdx;
        }
    }

    dense_softmax<<<256, 256, 0, stream>>>(Hf, dw, db, (float*)d_out);
}